// Round 1
// baseline (653.620 us; speedup 1.0000x reference)
//
#include <hip/hip_runtime.h>
#include <stdint.h>
#include <stddef.h>

typedef _Float16 half_t;
typedef _Float16 half8 __attribute__((ext_vector_type(8)));
typedef float float4v __attribute__((ext_vector_type(4)));

#define D_DIM 1792
#define B_DIM 8192

// ---------------------------------------------------------------------------
// Async global->LDS staging of ROWS*32 fp16 tile (rows along K, NT layout).
// 16B chunks with XOR-swizzle applied on the GLOBAL side (chunk kc of row r is
// fetched into slot kc, containing global chunk kc^(r&3)) so frag reads can
// de-swizzle with slot = chunk ^ (row&3) and stay ~bank-conflict-free.
// ---------------------------------------------------------------------------
__device__ __forceinline__ void stage_rows(const half_t* __restrict__ src, int row0, int ld,
                                           int k0, half_t* dst, int nchunks, int tid) {
  for (int base = 0; base < nchunks; base += 256) {
    int ch  = base + tid;
    int row = ch >> 2, kc = ch & 3;
    int swz = kc ^ (row & 3);
    const half_t* g = src + (size_t)(row0 + row) * ld + k0 + swz * 8;
    half_t* l = dst + (size_t)(base + (tid & 192)) * 8;   // wave-uniform base; HW adds lane*16B
    __builtin_amdgcn_global_load_lds(
        (const __attribute__((address_space(1))) uint32_t*)(const void*)g,
        (__attribute__((address_space(3))) uint32_t*)(void*)l, 16, 0, 0);
  }
}

__device__ __forceinline__ half8 frag32(const half_t* lds, int row, int chunk) {
  int slot = chunk ^ (row & 3);
  return *(const half8*)(lds + row * 32 + slot * 8);
}
__device__ __forceinline__ half8 frag128(const half_t* lds, int row, int chunk) {
  int slot = chunk ^ (row & 15);
  return *(const half8*)(lds + row * 128 + slot * 8);
}

// ---------------------------------------------------------------------------
// 1. Row-normalize U -> Vh (fp16). One block per row.
// ---------------------------------------------------------------------------
__global__ __launch_bounds__(256) void normalize_rows(const float* __restrict__ U,
                                                      half_t* __restrict__ Vh) {
  int r = blockIdx.x, t = threadIdx.x;
  float v[7];
  float s = 0.f;
#pragma unroll
  for (int i = 0; i < 7; ++i) {
    v[i] = U[(size_t)r * D_DIM + t + i * 256];
    s += v[i] * v[i];
  }
#pragma unroll
  for (int m = 32; m; m >>= 1) s += __shfl_xor(s, m);
  __shared__ float red[4];
  __shared__ float tot;
  if ((t & 63) == 0) red[t >> 6] = s;
  __syncthreads();
  if (t == 0) tot = 1.0f / sqrtf(red[0] + red[1] + red[2] + red[3]);
  __syncthreads();
  float rn = tot;
#pragma unroll
  for (int i = 0; i < 7; ++i)
    Vh[(size_t)r * D_DIM + t + i * 256] = (half_t)(v[i] * rn);
}

// ---------------------------------------------------------------------------
// 2. Transpose X (fp32, D x B) -> XT (fp16, B x D). 64x64 LDS tiles.
// ---------------------------------------------------------------------------
__global__ __launch_bounds__(256) void transpose_x(const float* __restrict__ X,
                                                   half_t* __restrict__ XT) {
  __shared__ half_t t[64][68];   // +4 halves pad -> 2-way-free bank pattern
  int r0 = blockIdx.x * 64, c0 = blockIdx.y * 64;
  int tid = threadIdx.x;
#pragma unroll
  for (int i = 0; i < 16; ++i) {
    int f = tid + i * 256;
    int rr = f >> 6, cc = f & 63;
    t[rr][cc] = (half_t)X[(size_t)(r0 + rr) * B_DIM + c0 + cc];
  }
  __syncthreads();
#pragma unroll
  for (int i = 0; i < 16; ++i) {
    int f = tid + i * 256;
    int cc = f >> 6, rr = f & 63;
    XT[(size_t)(c0 + cc) * D_DIM + r0 + rr] = t[rr][cc];
  }
}

// ---------------------------------------------------------------------------
// 3. Generic NT MFMA GEMM: C[m][n] = sum_k A[m][k]*B[n][k]  (both row-major-K)
//    128x128 tile, BK=32, 4 waves of 64x64, fp16 in / fp32 accum.
//    MODE 0: Cf = acc (gram)       MODE 1: Ch = acc (fp16 out, YT)
//    MODE 2: Cf = Xs - acc (final output)
// ---------------------------------------------------------------------------
template <int MODE>
__global__ __launch_bounds__(256) void gemm_nt(const half_t* __restrict__ A,
                                               const half_t* __restrict__ B,
                                               float* __restrict__ Cf, half_t* __restrict__ Ch,
                                               const float* __restrict__ Xs,
                                               int K, int lda, int ldb, int ldc) {
  __shared__ half_t sA[128 * 32];
  __shared__ half_t sB[128 * 32];
  int tid = threadIdx.x, lane = tid & 63, wave = tid >> 6;
  int ln15 = lane & 15, quad = lane >> 4;
  int m0 = blockIdx.y * 128, n0 = blockIdx.x * 128;
  int wr = (wave & 1) * 64, wc = (wave >> 1) * 64;
  float4v acc[4][4] = {};
  for (int kb = 0; kb < K / 32; ++kb) {
    stage_rows(A, m0, lda, kb * 32, sA, 512, tid);
    stage_rows(B, n0, ldb, kb * 32, sB, 512, tid);
    __syncthreads();
    half8 af[4], bf[4];
#pragma unroll
    for (int i = 0; i < 4; ++i) af[i] = frag32(sA, wr + i * 16 + ln15, quad);
#pragma unroll
    for (int j = 0; j < 4; ++j) bf[j] = frag32(sB, wc + j * 16 + ln15, quad);
#pragma unroll
    for (int i = 0; i < 4; ++i)
#pragma unroll
      for (int j = 0; j < 4; ++j)
        acc[i][j] = __builtin_amdgcn_mfma_f32_16x16x32_f16(af[i], bf[j], acc[i][j], 0, 0, 0);
    __syncthreads();
  }
#pragma unroll
  for (int i = 0; i < 4; ++i)
#pragma unroll
    for (int j = 0; j < 4; ++j)
#pragma unroll
      for (int rg = 0; rg < 4; ++rg) {
        int row = m0 + wr + i * 16 + quad * 4 + rg;
        int col = n0 + wc + j * 16 + ln15;
        size_t idx = (size_t)row * ldc + col;
        float v = acc[i][j][rg];
        if constexpr (MODE == 0) Cf[idx] = v;
        else if constexpr (MODE == 1) Ch[idx] = (half_t)v;
        else Cf[idx] = Xs[idx] - v;
      }
}

// ---------------------------------------------------------------------------
// 4. Build T16 (fp16): strict lower = 2*G, else 0.
// ---------------------------------------------------------------------------
__global__ __launch_bounds__(256) void build_T16(const float* __restrict__ G,
                                                 half_t* __restrict__ T16) {
  int r = blockIdx.y, c = blockIdx.x * 256 + threadIdx.x;
  float g = G[(size_t)r * D_DIM + c];
  T16[(size_t)r * D_DIM + c] = (c < r) ? (half_t)(2.0f * g) : (half_t)0.0f;
}

// ---------------------------------------------------------------------------
// 5. Invert 14 diagonal 128x128 unit-lower-triangular blocks of T.
//    One wave per column; forward substitution with 64-lane reductions.
// ---------------------------------------------------------------------------
__global__ __launch_bounds__(256) void diag_inv(const float* __restrict__ G,
                                                half_t* __restrict__ Dinv) {
  int b = blockIdx.x >> 5;        // block 0..13
  int cg = blockIdx.x & 31;       // column group
  int wave = threadIdx.x >> 6, ln = threadIdx.x & 63;
  int c = cg * 4 + wave;          // this wave's column (0..127)
  __shared__ float Ls[128][128];
  __shared__ float xw[4][128];
  for (int i = 0; i < 64; ++i) {
    int f = threadIdx.x + i * 256;
    int r = f >> 7, cc = f & 127;
    Ls[r][cc] = (cc < r) ? 2.0f * G[(size_t)(b * 128 + r) * D_DIM + b * 128 + cc] : 0.0f;
  }
  __syncthreads();
  float xlo = (ln == 0) ? 1.f : 0.f, xhi = 0.f;   // x[c+ln], x[c+64+ln]
  for (int r = c + 1; r < 128; ++r) {
    float ta = 0.f;
    int j0 = c + ln, j1 = c + 64 + ln;
    if (j0 < r) ta += Ls[r][j0] * xlo;
    if (j1 < r) ta += Ls[r][j1] * xhi;
#pragma unroll
    for (int m = 32; m; m >>= 1) ta += __shfl_xor(ta, m);
    float xr = -ta;
    if (j0 == r) xlo = xr;
    if (j1 == r) xhi = xr;
    if (ln == 0) xw[wave][r] = xr;
  }
  __syncthreads();
  for (int rr = ln; rr < 128; rr += 64) {
    float val = (rr < c) ? 0.f : ((rr == c) ? 1.f : xw[wave][rr]);
    Dinv[(size_t)b * 16384 + (size_t)rr * 128 + c] = (half_t)val;
  }
}

// ---------------------------------------------------------------------------
// 6. One blocked-forward-substitution step (fused update + diag-inverse apply).
//    WtT panel columns [ib*128,(ib+1)*128):
//    Ut[m][s] = 2*Vn[ib*128+s][m] - sum_{k<ib*128} WtT[m][k]*T16[ib*128+s][k]
//    WtT[m][ib*128+r] = sum_s Ut[m][s]*Dinv[ib][r][s]
//    Tile 64(m) x 128(panel); 28 WGs; 4 waves of 32x64.
// ---------------------------------------------------------------------------
__global__ __launch_bounds__(256) void solve_step(const half_t* __restrict__ T16,
                                                  const half_t* __restrict__ Vh,
                                                  const half_t* __restrict__ Dinv,
                                                  half_t* __restrict__ WtT, int ib) {
  __shared__ half_t sA[64 * 32];
  __shared__ half_t sB[128 * 32];
  __shared__ half_t Us[64 * 128];
  __shared__ half_t sD[128 * 128];
  int tid = threadIdx.x, lane = tid & 63, wave = tid >> 6;
  int ln15 = lane & 15, quad = lane >> 4;
  int m0 = blockIdx.x * 64;
  int wr = (wave & 1) * 32, wc = (wave >> 1) * 64;
  float4v acc[2][4] = {};
  int Ksteps = ib * 4;
  for (int kb = 0; kb < Ksteps; ++kb) {
    stage_rows(WtT, m0, D_DIM, kb * 32, sA, 256, tid);
    stage_rows(T16, ib * 128, D_DIM, kb * 32, sB, 512, tid);
    __syncthreads();
    half8 af[2], bf[4];
#pragma unroll
    for (int i = 0; i < 2; ++i) af[i] = frag32(sA, wr + i * 16 + ln15, quad);
#pragma unroll
    for (int j = 0; j < 4; ++j) bf[j] = frag32(sB, wc + j * 16 + ln15, quad);
#pragma unroll
    for (int i = 0; i < 2; ++i)
#pragma unroll
      for (int j = 0; j < 4; ++j)
        acc[i][j] = __builtin_amdgcn_mfma_f32_16x16x32_f16(af[i], bf[j], acc[i][j], 0, 0, 0);
    __syncthreads();
  }
  // phase 2: Ut = 2*VnT - acc  -> Us (swizzled A-operand layout)
#pragma unroll
  for (int i = 0; i < 2; ++i)
#pragma unroll
    for (int j = 0; j < 4; ++j)
#pragma unroll
      for (int rg = 0; rg < 4; ++rg) {
        int rl = wr + i * 16 + quad * 4 + rg;     // local m
        int cl = wc + j * 16 + ln15;              // local s (panel row)
        float vn = (float)Vh[(size_t)(ib * 128 + cl) * D_DIM + m0 + rl];
        float u = 2.f * vn - acc[i][j][rg];
        int sc = cl >> 3, off = cl & 7;
        Us[rl * 128 + ((sc ^ (rl & 15)) << 3) + off] = (half_t)u;
      }
  // phase 3: stage Dinv block (global-side swizzle for 128-wide rows)
  for (int it = 0; it < 8; ++it) {
    int ch = it * 256 + tid;
    int row = ch >> 4, sc = ch & 15;
    const half_t* g = Dinv + (size_t)ib * 16384 + (size_t)row * 128 + ((sc ^ (row & 15)) << 3);
    half_t* l = sD + (size_t)(it * 256 + (tid & 192)) * 8;
    __builtin_amdgcn_global_load_lds(
        (const __attribute__((address_space(1))) uint32_t*)(const void*)g,
        (__attribute__((address_space(3))) uint32_t*)(void*)l, 16, 0, 0);
  }
  __syncthreads();
  // phase 4: WtT-panel = Ut * Dinv^T  (K=128)
  float4v a2[2][4] = {};
#pragma unroll
  for (int kk = 0; kk < 4; ++kk) {
    half8 af[2], bf[4];
#pragma unroll
    for (int i = 0; i < 2; ++i) af[i] = frag128(Us, wr + i * 16 + ln15, kk * 4 + quad);
#pragma unroll
    for (int j = 0; j < 4; ++j) bf[j] = frag128(sD, wc + j * 16 + ln15, kk * 4 + quad);
#pragma unroll
    for (int i = 0; i < 2; ++i)
#pragma unroll
      for (int j = 0; j < 4; ++j)
        a2[i][j] = __builtin_amdgcn_mfma_f32_16x16x32_f16(af[i], bf[j], a2[i][j], 0, 0, 0);
  }
#pragma unroll
  for (int i = 0; i < 2; ++i)
#pragma unroll
    for (int j = 0; j < 4; ++j)
#pragma unroll
      for (int rg = 0; rg < 4; ++rg) {
        int rl = wr + i * 16 + quad * 4 + rg;
        int cl = wc + j * 16 + ln15;
        WtT[(size_t)(m0 + rl) * D_DIM + ib * 128 + cl] = (half_t)a2[i][j][rg];
      }
}

// ---------------------------------------------------------------------------
extern "C" void kernel_launch(void* const* d_in, const int* in_sizes, int n_in,
                              void* d_out, int out_size, void* d_ws, size_t ws_size,
                              hipStream_t stream) {
  (void)in_sizes; (void)n_in; (void)out_size; (void)ws_size;
  const float* X = (const float*)d_in[0];   // (1792, 8192) fp32
  const float* U = (const float*)d_in[1];   // (1792, 1792) fp32
  float* out = (float*)d_out;               // (1792, 8192) fp32

  char* ws = (char*)d_ws;
  half_t* XT   = (half_t*)(ws);                               // 29,360,128 B
  half_t* YT   = (half_t*)(ws + 29360128);                    // 29,360,128 B
  half_t* Vh   = (half_t*)(ws + 58720256);                    //  6,422,528 B
  half_t* T16  = (half_t*)(ws + 65142784);                    //  6,422,528 B
  half_t* WtT  = (half_t*)(ws + 71565312);                    //  6,422,528 B
  half_t* Dinv = (half_t*)(ws + 77987840);                    //    458,752 B
  float*  G    = (float*)(ws + 78446592);                     // 12,845,056 B  (total ~91.3MB)

  normalize_rows<<<dim3(D_DIM), dim3(256), 0, stream>>>(U, Vh);
  transpose_x<<<dim3(D_DIM / 64, B_DIM / 64), dim3(256), 0, stream>>>(X, XT);
  // G = Vn Vn^T
  gemm_nt<0><<<dim3(14, 14), dim3(256), 0, stream>>>(Vh, Vh, G, nullptr, nullptr,
                                                     D_DIM, D_DIM, D_DIM, D_DIM);
  build_T16<<<dim3(7, D_DIM), dim3(256), 0, stream>>>(G, T16);
  diag_inv<<<dim3(448), dim3(256), 0, stream>>>(G, Dinv);
  // blocked forward substitution: WtT = (T^{-1} 2Vn)^T
  for (int ib = 0; ib < 14; ++ib)
    solve_step<<<dim3(28), dim3(256), 0, stream>>>(T16, Vh, Dinv, WtT, ib);
  // YT = (Vn X)^T  : YT[j][i] = sum_k XT[j][k] * Vh[i][k]
  gemm_nt<1><<<dim3(14, 64), dim3(256), 0, stream>>>(XT, Vh, nullptr, YT, nullptr,
                                                     D_DIM, D_DIM, D_DIM, D_DIM);
  // out = X - Wt^T Y : out[i][j] = X[i][j] - sum_k WtT[i][k] * YT[j][k]
  gemm_nt<2><<<dim3(64, 14), dim3(256), 0, stream>>>(WtT, YT, out, nullptr, X,
                                                     D_DIM, D_DIM, D_DIM, B_DIM);
}

// Round 2
// 607.982 us; speedup vs baseline: 1.0751x; 1.0751x over previous
//
#include <hip/hip_runtime.h>
#include <stdint.h>
#include <stddef.h>

typedef _Float16 half_t;
typedef _Float16 half8 __attribute__((ext_vector_type(8)));
typedef float float4v __attribute__((ext_vector_type(4)));

#define D_DIM 1792
#define B_DIM 8192
#define LD D_DIM

// ---------------------------------------------------------------------------
// Async global->LDS staging of ROWS*32 fp16 tile (rows along K, NT layout).
// XOR-swizzle on the GLOBAL side; slot = chunk ^ ((row>>1)&3) makes every
// 8-lane b128 phase cover all 8 bank-quads (conflict-free; R1 fix — the old
// (row&3) swizzle collided lanes {0,4},{1,5},... -> 4 extra cyc/read).
// ---------------------------------------------------------------------------
__device__ __forceinline__ void stage_rows(const half_t* __restrict__ src, int row0, int ld,
                                           int k0, half_t* dst, int nchunks, int tid) {
  for (int base = 0; base < nchunks; base += 256) {
    int ch  = base + tid;
    int row = ch >> 2, kc = ch & 3;
    int swz = kc ^ ((row >> 1) & 3);
    const half_t* g = src + (size_t)(row0 + row) * ld + k0 + swz * 8;
    half_t* l = dst + (size_t)(base + (tid & 192)) * 8;   // wave-uniform base; HW adds lane*16B
    __builtin_amdgcn_global_load_lds(
        (const __attribute__((address_space(1))) uint32_t*)(const void*)g,
        (__attribute__((address_space(3))) uint32_t*)(void*)l, 16, 0, 0);
  }
}

__device__ __forceinline__ half8 frag32(const half_t* lds, int row, int chunk) {
  int slot = chunk ^ ((row >> 1) & 3);
  return *(const half8*)(lds + row * 32 + slot * 8);
}

// ---------------------------------------------------------------------------
// 1. Row-normalize U -> Vh (fp16). One block per row.
// ---------------------------------------------------------------------------
__global__ __launch_bounds__(256) void normalize_rows(const float* __restrict__ U,
                                                      half_t* __restrict__ Vh) {
  int r = blockIdx.x, t = threadIdx.x;
  float v[7];
  float s = 0.f;
#pragma unroll
  for (int i = 0; i < 7; ++i) {
    v[i] = U[(size_t)r * D_DIM + t + i * 256];
    s += v[i] * v[i];
  }
#pragma unroll
  for (int m = 32; m; m >>= 1) s += __shfl_xor(s, m);
  __shared__ float red[4];
  __shared__ float tot;
  if ((t & 63) == 0) red[t >> 6] = s;
  __syncthreads();
  if (t == 0) tot = 1.0f / sqrtf(red[0] + red[1] + red[2] + red[3]);
  __syncthreads();
  float rn = tot;
#pragma unroll
  for (int i = 0; i < 7; ++i)
    Vh[(size_t)r * D_DIM + t + i * 256] = (half_t)(v[i] * rn);
}

// ---------------------------------------------------------------------------
// 2. Transpose X (fp32, D x B) -> XT (fp16, B x D). 64x64 LDS tiles.
// ---------------------------------------------------------------------------
__global__ __launch_bounds__(256) void transpose_x(const float* __restrict__ X,
                                                   half_t* __restrict__ XT) {
  __shared__ half_t t[64][68];
  int r0 = blockIdx.x * 64, c0 = blockIdx.y * 64;
  int tid = threadIdx.x;
#pragma unroll
  for (int i = 0; i < 16; ++i) {
    int f = tid + i * 256;
    int rr = f >> 6, cc = f & 63;
    t[rr][cc] = (half_t)X[(size_t)(r0 + rr) * B_DIM + c0 + cc];
  }
  __syncthreads();
#pragma unroll
  for (int i = 0; i < 16; ++i) {
    int f = tid + i * 256;
    int cc = f >> 6, rr = f & 63;
    XT[(size_t)(c0 + cc) * D_DIM + r0 + rr] = t[rr][cc];
  }
}

// ---------------------------------------------------------------------------
// 2b. Transpose Vh (fp16, D x D) -> VhT.
// ---------------------------------------------------------------------------
__global__ __launch_bounds__(256) void transpose_h(const half_t* __restrict__ Vh,
                                                   half_t* __restrict__ VhT) {
  __shared__ half_t t[64][68];
  int r0 = blockIdx.x * 64, c0 = blockIdx.y * 64;
  int tid = threadIdx.x;
#pragma unroll
  for (int i = 0; i < 16; ++i) {
    int f = tid + i * 256;
    int rr = f >> 6, cc = f & 63;
    t[rr][cc] = Vh[(size_t)(r0 + rr) * D_DIM + c0 + cc];
  }
  __syncthreads();
#pragma unroll
  for (int i = 0; i < 16; ++i) {
    int f = tid + i * 256;
    int cc = f >> 6, rr = f & 63;
    VhT[(size_t)(c0 + cc) * D_DIM + r0 + rr] = t[rr][cc];
  }
}

// ---------------------------------------------------------------------------
// 3. Big NT MFMA GEMM: C[m][n] = sum_k A[m][k]*B[n][k], 128x128 tile, BK=32.
//    MODE 0: Cf = acc, triangular skip (gram)   MODE 1: Ch = acc (fp16, YT)
//    MODE 2: Cf = Xs - acc (final output)
// ---------------------------------------------------------------------------
template <int MODE>
__global__ __launch_bounds__(256) void gemm_nt(const half_t* __restrict__ A,
                                               const half_t* __restrict__ B,
                                               float* __restrict__ Cf, half_t* __restrict__ Ch,
                                               const float* __restrict__ Xs,
                                               int K, int lda, int ldb, int ldc) {
  int m0 = blockIdx.y * 128, n0 = blockIdx.x * 128;
  if constexpr (MODE == 0) { if (n0 > m0) return; }   // gram: lower+diag blocks only
  __shared__ half_t sA[128 * 32];
  __shared__ half_t sB[128 * 32];
  int tid = threadIdx.x, lane = tid & 63, wave = tid >> 6;
  int ln15 = lane & 15, quad = lane >> 4;
  int wr = (wave & 1) * 64, wc = (wave >> 1) * 64;
  float4v acc[4][4] = {};
  for (int kb = 0; kb < K / 32; ++kb) {
    stage_rows(A, m0, lda, kb * 32, sA, 512, tid);
    stage_rows(B, n0, ldb, kb * 32, sB, 512, tid);
    __syncthreads();
    half8 af[4], bf[4];
#pragma unroll
    for (int i = 0; i < 4; ++i) af[i] = frag32(sA, wr + i * 16 + ln15, quad);
#pragma unroll
    for (int j = 0; j < 4; ++j) bf[j] = frag32(sB, wc + j * 16 + ln15, quad);
#pragma unroll
    for (int i = 0; i < 4; ++i)
#pragma unroll
      for (int j = 0; j < 4; ++j)
        acc[i][j] = __builtin_amdgcn_mfma_f32_16x16x32_f16(af[i], bf[j], acc[i][j], 0, 0, 0);
    __syncthreads();
  }
#pragma unroll
  for (int i = 0; i < 4; ++i)
#pragma unroll
    for (int j = 0; j < 4; ++j)
#pragma unroll
      for (int rg = 0; rg < 4; ++rg) {
        int row = m0 + wr + i * 16 + quad * 4 + rg;
        int col = n0 + wc + j * 16 + ln15;
        size_t idx = (size_t)row * ldc + col;
        float v = acc[i][j][rg];
        if constexpr (MODE == 0) Cf[idx] = v;
        else if constexpr (MODE == 1) Ch[idx] = (half_t)v;
        else Cf[idx] = Xs[idx] - v;
      }
}

// ---------------------------------------------------------------------------
// 3b. Batched small NT GEMM for the triangular-inverse combines + WtT.
//     C[m][n] = alpha * sum_k A[m][k]*B[n][k], fp16 out.
//     kmode: 0 full K; 1 kmax=n0+128; 2 kmax=m0+128; 3 kmin=m0.
//     blockIdx.z selects the pair: ptr += z * z-stride (elements).
// ---------------------------------------------------------------------------
__global__ __launch_bounds__(256) void gemm_b(const half_t* A, const half_t* B, half_t* C,
                                              int lda, int ldb, int ldc, int K, int kmode,
                                              float alpha, long long zA, long long zB,
                                              long long zC) {
  A += (long long)blockIdx.z * zA;
  B += (long long)blockIdx.z * zB;
  C += (long long)blockIdx.z * zC;
  __shared__ half_t sA[128 * 32];
  __shared__ half_t sB[128 * 32];
  int tid = threadIdx.x, lane = tid & 63, wave = tid >> 6;
  int ln15 = lane & 15, quad = lane >> 4;
  int m0 = blockIdx.y * 128, n0 = blockIdx.x * 128;
  int wr = (wave & 1) * 64, wc = (wave >> 1) * 64;
  int k0 = (kmode == 3) ? m0 : 0;
  int k1 = (kmode == 1) ? (n0 + 128) : (kmode == 2) ? (m0 + 128) : K;
  float4v acc[4][4] = {};
  for (int kb = k0 / 32; kb < k1 / 32; ++kb) {
    stage_rows(A, m0, lda, kb * 32, sA, 512, tid);
    stage_rows(B, n0, ldb, kb * 32, sB, 512, tid);
    __syncthreads();
    half8 af[4], bf[4];
#pragma unroll
    for (int i = 0; i < 4; ++i) af[i] = frag32(sA, wr + i * 16 + ln15, quad);
#pragma unroll
    for (int j = 0; j < 4; ++j) bf[j] = frag32(sB, wc + j * 16 + ln15, quad);
#pragma unroll
    for (int i = 0; i < 4; ++i)
#pragma unroll
      for (int j = 0; j < 4; ++j)
        acc[i][j] = __builtin_amdgcn_mfma_f32_16x16x32_f16(af[i], bf[j], acc[i][j], 0, 0, 0);
    __syncthreads();
  }
#pragma unroll
  for (int i = 0; i < 4; ++i)
#pragma unroll
    for (int j = 0; j < 4; ++j)
#pragma unroll
      for (int rg = 0; rg < 4; ++rg) {
        int row = m0 + wr + i * 16 + quad * 4 + rg;
        int col = n0 + wc + j * 16 + ln15;
        C[(size_t)row * ldc + col] = (half_t)(alpha * acc[i][j][rg]);
      }
}

// ---------------------------------------------------------------------------
// 4. Build T16 (fp16): strict lower = 2*G, else 0.
// ---------------------------------------------------------------------------
__global__ __launch_bounds__(256) void build_T16(const float* __restrict__ G,
                                                 half_t* __restrict__ T16) {
  int r = blockIdx.y, c = blockIdx.x * 256 + threadIdx.x;
  float g = G[(size_t)r * D_DIM + c];
  T16[(size_t)r * D_DIM + c] = (c < r) ? (half_t)(2.0f * g) : (half_t)0.0f;
}

// ---------------------------------------------------------------------------
// 5. Invert 14 diagonal 128x128 unit-lower-triangular blocks of T (from T16).
//    Writes the inverse block (full square incl. zero upper half) into both
//    Tinv and TinvT. One wave per column; forward substitution.
// ---------------------------------------------------------------------------
__global__ __launch_bounds__(256) void diag_inv(const half_t* __restrict__ T16,
                                                half_t* __restrict__ Tinv,
                                                half_t* __restrict__ TinvT) {
  int b = blockIdx.x >> 5;        // block 0..13
  int cg = blockIdx.x & 31;       // column group
  int wave = threadIdx.x >> 6, ln = threadIdx.x & 63;
  int c = cg * 4 + wave;          // this wave's column (0..127)
  __shared__ float Ls[128][128];
  __shared__ float xw[4][128];
  for (int i = 0; i < 64; ++i) {
    int f = threadIdx.x + i * 256;
    int r = f >> 7, cc = f & 127;
    Ls[r][cc] = (cc < r) ? (float)T16[(size_t)(b * 128 + r) * D_DIM + b * 128 + cc] : 0.0f;
  }
  __syncthreads();
  float xlo = (ln == 0) ? 1.f : 0.f, xhi = 0.f;
  for (int r = c + 1; r < 128; ++r) {
    float ta = 0.f;
    int j0 = c + ln, j1 = c + 64 + ln;
    if (j0 < r) ta += Ls[r][j0] * xlo;
    if (j1 < r) ta += Ls[r][j1] * xhi;
#pragma unroll
    for (int m = 32; m; m >>= 1) ta += __shfl_xor(ta, m);
    float xr = -ta;
    if (j0 == r) xlo = xr;
    if (j1 == r) xhi = xr;
    if (ln == 0) xw[wave][r] = xr;
  }
  __syncthreads();
  for (int rr = ln; rr < 128; rr += 64) {
    float val = (rr < c) ? 0.f : ((rr == c) ? 1.f : xw[wave][rr]);
    half_t hv = (half_t)val;
    Tinv[(size_t)(b * 128 + rr) * D_DIM + b * 128 + c] = hv;
    TinvT[(size_t)(b * 128 + c) * D_DIM + b * 128 + rr] = hv;
  }
}

// ---------------------------------------------------------------------------
// Host-side combine helper: one level of recursive triangular inversion.
//   [[A,0],[Bb,C]]^-1 = [[Ai,0],[-Ci*Bb*Ai, Ci]]
//   M1T = (Bb*Ai)^T via NT(TinvT_A, T16_Bb); O = -Ci*M1 into Tinv;
//   OT into TinvT (skipped when no later level reads it).
// ---------------------------------------------------------------------------
static inline void combine_level(half_t* Tinv, half_t* TinvT, half_t* T16, half_t* M1T,
                                 int p, int q, int aOff0, int step, int n, bool doOT,
                                 hipStream_t stream) {
  long long zs = (long long)step * (LD + 1);
  long long zm = (long long)p * q;
  // M1T[c][s] = sum_{k>=m0} AiT[c][k] * Bb[s][k]   (M=p, N=q, K=p, kmin=m0)
  gemm_b<<<dim3(q / 128, p / 128, n), dim3(256), 0, stream>>>(
      TinvT + (size_t)aOff0 * (LD + 1), T16 + (size_t)(aOff0 + p) * LD + aOff0, M1T,
      LD, LD, q, p, 3, 1.0f, zs, zs, zm);
  // O[s][c] = -sum_{k<m0+128} Ci[s][k] * M1T[c][k]  (M=q, N=p, K=q, kmax=m0+128)
  gemm_b<<<dim3(p / 128, q / 128, n), dim3(256), 0, stream>>>(
      Tinv + (size_t)(aOff0 + p) * (LD + 1), M1T, Tinv + (size_t)(aOff0 + p) * LD + aOff0,
      LD, q, LD, q, 2, -1.0f, zs, zm, zs);
  if (doOT) {
    // OT[c][s] = -sum_{k<n0+128} M1T[c][k] * Ci[s][k]  (M=p, N=q, K=q, kmax=n0+128)
    gemm_b<<<dim3(q / 128, p / 128, n), dim3(256), 0, stream>>>(
        M1T, Tinv + (size_t)(aOff0 + p) * (LD + 1), TinvT + (size_t)aOff0 * LD + (aOff0 + p),
        q, LD, LD, q, 1, -1.0f, zm, zs, zs);
  }
}

// ---------------------------------------------------------------------------
extern "C" void kernel_launch(void* const* d_in, const int* in_sizes, int n_in,
                              void* d_out, int out_size, void* d_ws, size_t ws_size,
                              hipStream_t stream) {
  (void)in_sizes; (void)n_in; (void)out_size; (void)ws_size;
  const float* X = (const float*)d_in[0];   // (1792, 8192) fp32
  const float* U = (const float*)d_in[1];   // (1792, 1792) fp32
  float* out = (float*)d_out;               // (1792, 8192) fp32

  char* ws = (char*)d_ws;
  half_t* XT    = (half_t*)(ws);                    // 29,360,128 B
  half_t* VhT   = (half_t*)(ws);                    // aliases XT (XT dead after MODE1)
  half_t* YT    = (half_t*)(ws + 29360128);         // 29,360,128 B
  half_t* Vh    = (half_t*)(ws + 58720256);         //  6,422,528 B
  half_t* TinvT = (half_t*)(ws + 58720256);         // aliases Vh (Vh dead after transpose_h)
  half_t* T16   = (half_t*)(ws + 65142784);         //  6,422,528 B
  half_t* WtT   = (half_t*)(ws + 71565312);         //  6,422,528 B
  float*  G     = (float*)(ws + 77987840);          // 12,845,056 B (dead after build_T16)
  half_t* M1T   = (half_t*)(ws + 77987840);         // aliases G, max 1.6 MB
  half_t* Tinv  = (half_t*)(ws + 80084992);         // aliases G+2MB, 6,422,528 B
  // total footprint: 90,832,896 B

  normalize_rows<<<dim3(D_DIM), dim3(256), 0, stream>>>(U, Vh);
  transpose_x<<<dim3(D_DIM / 64, B_DIM / 64), dim3(256), 0, stream>>>(X, XT);
  // G = Vn Vn^T (lower+diag blocks only)
  gemm_nt<0><<<dim3(14, 14), dim3(256), 0, stream>>>(Vh, Vh, G, nullptr, nullptr,
                                                     D_DIM, D_DIM, D_DIM, D_DIM);
  // YT = (Vn X)^T  (must precede transpose_h / diag_inv which overwrite XT/Vh space)
  gemm_nt<1><<<dim3(14, 64), dim3(256), 0, stream>>>(XT, Vh, nullptr, YT, nullptr,
                                                     D_DIM, D_DIM, D_DIM, D_DIM);
  transpose_h<<<dim3(28, 28), dim3(256), 0, stream>>>(Vh, VhT);
  build_T16<<<dim3(7, D_DIM), dim3(256), 0, stream>>>(G, T16);
  diag_inv<<<dim3(448), dim3(256), 0, stream>>>(T16, Tinv, TinvT);
  // recursive block inversion of T: 128 -> 256 -> 512 -> 1024/768 -> 1792
  combine_level(Tinv, TinvT, T16, M1T, 128, 128, 0, 256, 7, true, stream);   // L1
  combine_level(Tinv, TinvT, T16, M1T, 256, 256, 0, 512, 3, true, stream);   // L2
  combine_level(Tinv, TinvT, T16, M1T, 512, 512, 0, 0, 1, true, stream);     // L3a
  combine_level(Tinv, TinvT, T16, M1T, 512, 256, 1024, 0, 1, false, stream); // L3b
  combine_level(Tinv, TinvT, T16, M1T, 1024, 768, 0, 0, 1, false, stream);   // L4
  // WtT[m][r] = 2 * sum_{k<=r} VhT[m][k] * Tinv[r][k]
  gemm_b<<<dim3(14, 14, 1), dim3(256), 0, stream>>>(VhT, Tinv, WtT, LD, LD, LD,
                                                    D_DIM, 1, 2.0f, 0, 0, 0);
  // out = X - Wt^T Y
  gemm_nt<2><<<dim3(64, 14), dim3(256), 0, stream>>>(WtT, YT, out, nullptr, X,
                                                     D_DIM, D_DIM, D_DIM, B_DIM);
}

// Round 3
// 541.058 us; speedup vs baseline: 1.2080x; 1.1237x over previous
//
#include <hip/hip_runtime.h>
#include <stdint.h>
#include <stddef.h>

typedef _Float16 half_t;
typedef _Float16 half8 __attribute__((ext_vector_type(8)));
typedef float float4v __attribute__((ext_vector_type(4)));

#define D_DIM 1792
#define B_DIM 8192
#define LD D_DIM

// ---------------------------------------------------------------------------
// Async global->LDS staging of ROWS*32 fp16 tile (rows along K, NT layout).
// slot = chunk ^ ((row>>1)&3): every 8-lane b128 phase covers all 8 bank-quads
// (conflict-free — verified R2: SQ_LDS_BANK_CONFLICT 6.4e6 -> 0).
// ---------------------------------------------------------------------------
__device__ __forceinline__ void stage_rows(const half_t* __restrict__ src, int row0, int ld,
                                           int k0, half_t* dst, int nchunks, int tid) {
  for (int base = 0; base < nchunks; base += 256) {
    int ch  = base + tid;
    int row = ch >> 2, kc = ch & 3;
    int swz = kc ^ ((row >> 1) & 3);
    const half_t* g = src + (size_t)(row0 + row) * ld + k0 + swz * 8;
    half_t* l = dst + (size_t)(base + (tid & 192)) * 8;   // wave-uniform base; HW adds lane*16B
    __builtin_amdgcn_global_load_lds(
        (const __attribute__((address_space(1))) uint32_t*)(const void*)g,
        (__attribute__((address_space(3))) uint32_t*)(void*)l, 16, 0, 0);
  }
}

__device__ __forceinline__ half8 frag32(const half_t* lds, int row, int chunk) {
  int slot = chunk ^ ((row >> 1) & 3);
  return *(const half8*)(lds + row * 32 + slot * 8);
}
// 128-wide LDS rows (Us / Dinv in the solve): 2-way aliasing only (free).
__device__ __forceinline__ half8 frag128(const half_t* lds, int row, int chunk) {
  int slot = chunk ^ (row & 15);
  return *(const half8*)(lds + row * 128 + slot * 8);
}

// ---------------------------------------------------------------------------
// 1. Row-normalize U -> Vh (fp16). One block per row.
// ---------------------------------------------------------------------------
__global__ __launch_bounds__(256) void normalize_rows(const float* __restrict__ U,
                                                      half_t* __restrict__ Vh) {
  int r = blockIdx.x, t = threadIdx.x;
  float v[7];
  float s = 0.f;
#pragma unroll
  for (int i = 0; i < 7; ++i) {
    v[i] = U[(size_t)r * D_DIM + t + i * 256];
    s += v[i] * v[i];
  }
#pragma unroll
  for (int m = 32; m; m >>= 1) s += __shfl_xor(s, m);
  __shared__ float red[4];
  __shared__ float tot;
  if ((t & 63) == 0) red[t >> 6] = s;
  __syncthreads();
  if (t == 0) tot = 1.0f / sqrtf(red[0] + red[1] + red[2] + red[3]);
  __syncthreads();
  float rn = tot;
#pragma unroll
  for (int i = 0; i < 7; ++i)
    Vh[(size_t)r * D_DIM + t + i * 256] = (half_t)(v[i] * rn);
}

// ---------------------------------------------------------------------------
// 2. Transpose X (fp32, D x B) -> XT (fp16, B x D). 64x64 LDS tiles.
// ---------------------------------------------------------------------------
__global__ __launch_bounds__(256) void transpose_x(const float* __restrict__ X,
                                                   half_t* __restrict__ XT) {
  __shared__ half_t t[64][68];
  int r0 = blockIdx.x * 64, c0 = blockIdx.y * 64;
  int tid = threadIdx.x;
#pragma unroll
  for (int i = 0; i < 16; ++i) {
    int f = tid + i * 256;
    int rr = f >> 6, cc = f & 63;
    t[rr][cc] = (half_t)X[(size_t)(r0 + rr) * B_DIM + c0 + cc];
  }
  __syncthreads();
#pragma unroll
  for (int i = 0; i < 16; ++i) {
    int f = tid + i * 256;
    int cc = f >> 6, rr = f & 63;
    XT[(size_t)(c0 + cc) * D_DIM + r0 + rr] = t[rr][cc];
  }
}

// ---------------------------------------------------------------------------
// 2b. Transpose Vh (fp16, D x D) -> VhT.
// ---------------------------------------------------------------------------
__global__ __launch_bounds__(256) void transpose_h(const half_t* __restrict__ Vh,
                                                   half_t* __restrict__ VhT) {
  __shared__ half_t t[64][68];
  int r0 = blockIdx.x * 64, c0 = blockIdx.y * 64;
  int tid = threadIdx.x;
#pragma unroll
  for (int i = 0; i < 16; ++i) {
    int f = tid + i * 256;
    int rr = f >> 6, cc = f & 63;
    t[rr][cc] = Vh[(size_t)(r0 + rr) * D_DIM + c0 + cc];
  }
  __syncthreads();
#pragma unroll
  for (int i = 0; i < 16; ++i) {
    int f = tid + i * 256;
    int cc = f >> 6, rr = f & 63;
    VhT[(size_t)(c0 + cc) * D_DIM + r0 + rr] = t[rr][cc];
  }
}

// ---------------------------------------------------------------------------
// 3. Big NT MFMA GEMM: acc[m][n] = sum_k A[m][k]*B[n][k], 128x128 tile, BK=32.
//    MODE 0 (gram->T16): triangular block skip; Ch = (c<r) ? 2*acc : 0  (fp16)
//    MODE 1 (Pf build):  Ch = (r==c ? 1 : 0) - acc                      (fp16)
//    MODE 2 (final):     Cf = acc                                       (fp32)
// ---------------------------------------------------------------------------
template <int MODE>
__global__ __launch_bounds__(256) void gemm_nt(const half_t* __restrict__ A,
                                               const half_t* __restrict__ B,
                                               float* __restrict__ Cf, half_t* __restrict__ Ch,
                                               int K, int lda, int ldb, int ldc) {
  int m0 = blockIdx.y * 128, n0 = blockIdx.x * 128;
  if constexpr (MODE == 0) { if (n0 > m0) return; }   // gram: lower+diag blocks only
  __shared__ half_t sA[128 * 32];
  __shared__ half_t sB[128 * 32];
  int tid = threadIdx.x, lane = tid & 63, wave = tid >> 6;
  int ln15 = lane & 15, quad = lane >> 4;
  int wr = (wave & 1) * 64, wc = (wave >> 1) * 64;
  float4v acc[4][4] = {};
  for (int kb = 0; kb < K / 32; ++kb) {
    stage_rows(A, m0, lda, kb * 32, sA, 512, tid);
    stage_rows(B, n0, ldb, kb * 32, sB, 512, tid);
    __syncthreads();
    half8 af[4], bf[4];
#pragma unroll
    for (int i = 0; i < 4; ++i) af[i] = frag32(sA, wr + i * 16 + ln15, quad);
#pragma unroll
    for (int j = 0; j < 4; ++j) bf[j] = frag32(sB, wc + j * 16 + ln15, quad);
#pragma unroll
    for (int i = 0; i < 4; ++i)
#pragma unroll
      for (int j = 0; j < 4; ++j)
        acc[i][j] = __builtin_amdgcn_mfma_f32_16x16x32_f16(af[i], bf[j], acc[i][j], 0, 0, 0);
    __syncthreads();
  }
#pragma unroll
  for (int i = 0; i < 4; ++i)
#pragma unroll
    for (int j = 0; j < 4; ++j)
#pragma unroll
      for (int rg = 0; rg < 4; ++rg) {
        int row = m0 + wr + i * 16 + quad * 4 + rg;
        int col = n0 + wc + j * 16 + ln15;
        size_t idx = (size_t)row * ldc + col;
        float v = acc[i][j][rg];
        if constexpr (MODE == 0) Ch[idx] = (col < row) ? (half_t)(2.0f * v) : (half_t)0.0f;
        else if constexpr (MODE == 1) Ch[idx] = (half_t)(((row == col) ? 1.0f : 0.0f) - v);
        else Cf[idx] = v;
      }
}

// ---------------------------------------------------------------------------
// 4. Invert 14 diagonal 128x128 unit-lower-triangular blocks of T (from T16).
//    One wave per column; forward substitution. -> Dinv (fp16, 14x128x128)
// ---------------------------------------------------------------------------
__global__ __launch_bounds__(256) void diag_inv(const half_t* __restrict__ T16,
                                                half_t* __restrict__ Dinv) {
  int b = blockIdx.x >> 5;        // block 0..13
  int cg = blockIdx.x & 31;       // column group
  int wave = threadIdx.x >> 6, ln = threadIdx.x & 63;
  int c = cg * 4 + wave;          // this wave's column (0..127)
  __shared__ float Ls[128][128];
  __shared__ float xw[4][128];
  for (int i = 0; i < 64; ++i) {
    int f = threadIdx.x + i * 256;
    int r = f >> 7, cc = f & 127;
    Ls[r][cc] = (cc < r) ? (float)T16[(size_t)(b * 128 + r) * D_DIM + b * 128 + cc] : 0.0f;
  }
  __syncthreads();
  float xlo = (ln == 0) ? 1.f : 0.f, xhi = 0.f;
  for (int r = c + 1; r < 128; ++r) {
    float ta = 0.f;
    int j0 = c + ln, j1 = c + 64 + ln;
    if (j0 < r) ta += Ls[r][j0] * xlo;
    if (j1 < r) ta += Ls[r][j1] * xhi;
#pragma unroll
    for (int m = 32; m; m >>= 1) ta += __shfl_xor(ta, m);
    float xr = -ta;
    if (j0 == r) xlo = xr;
    if (j1 == r) xhi = xr;
    if (ln == 0) xw[wave][r] = xr;
  }
  __syncthreads();
  for (int rr = ln; rr < 128; rr += 64) {
    float val = (rr < c) ? 0.f : ((rr == c) ? 1.f : xw[wave][rr]);
    Dinv[(size_t)b * 16384 + (size_t)rr * 128 + c] = (half_t)val;
  }
}

// ---------------------------------------------------------------------------
// 5. FUSED blocked forward substitution — ONE launch (was 14 in R1, 15 in R2).
//    Key fact: WtT row m = Wt column m, and columns of T*Wt=2Vn are independent
//    triangular solves -> the panel dependency is within the same m-rows only.
//    Each block owns 64 m-rows and loops all 14 panels internally; the WtT
//    global round-trip is same-CU (L1-coherent), ordered by __syncthreads'
//    vmcnt(0) drain.
//    Per panel ib:
//      Ut[m][s] = 2*Vn[ib*128+s][m] - sum_{k<ib*128} WtT[m][k]*T16[ib*128+s][k]
//      WtT[m][ib*128+r] = sum_s Ut[m][s]*Dinv[ib][r][s]
// ---------------------------------------------------------------------------
__global__ __launch_bounds__(256) void fused_solve(const half_t* __restrict__ T16,
                                                   const half_t* __restrict__ Vh,
                                                   const half_t* __restrict__ Dinv,
                                                   half_t* __restrict__ WtT) {
  __shared__ half_t sA[64 * 32];
  __shared__ half_t sB[128 * 32];
  __shared__ half_t Us[64 * 128];
  __shared__ half_t sD[128 * 128];
  int tid = threadIdx.x, lane = tid & 63, wave = tid >> 6;
  int ln15 = lane & 15, quad = lane >> 4;
  int m0 = blockIdx.x * 64;
  int wr = (wave & 1) * 32, wc = (wave >> 1) * 64;
  for (int ib = 0; ib < 14; ++ib) {
    __syncthreads();   // drain prev panel's WtT stores before re-reading them
    float4v acc[2][4] = {};
    int Ksteps = ib * 4;
    for (int kb = 0; kb < Ksteps; ++kb) {
      stage_rows(WtT, m0, D_DIM, kb * 32, sA, 256, tid);
      stage_rows(T16, ib * 128, D_DIM, kb * 32, sB, 512, tid);
      __syncthreads();
      half8 af[2], bf[4];
#pragma unroll
      for (int i = 0; i < 2; ++i) af[i] = frag32(sA, wr + i * 16 + ln15, quad);
#pragma unroll
      for (int j = 0; j < 4; ++j) bf[j] = frag32(sB, wc + j * 16 + ln15, quad);
#pragma unroll
      for (int i = 0; i < 2; ++i)
#pragma unroll
        for (int j = 0; j < 4; ++j)
          acc[i][j] = __builtin_amdgcn_mfma_f32_16x16x32_f16(af[i], bf[j], acc[i][j], 0, 0, 0);
      __syncthreads();
    }
    // phase 2: Ut = 2*VnT - acc  -> Us (A-operand layout, swizzled)
#pragma unroll
    for (int i = 0; i < 2; ++i)
#pragma unroll
      for (int j = 0; j < 4; ++j)
#pragma unroll
        for (int rg = 0; rg < 4; ++rg) {
          int rl = wr + i * 16 + quad * 4 + rg;     // local m
          int cl = wc + j * 16 + ln15;              // local s (panel row)
          float vn = (float)Vh[(size_t)(ib * 128 + cl) * D_DIM + m0 + rl];
          float u = 2.f * vn - acc[i][j][rg];
          int sc = cl >> 3, off = cl & 7;
          Us[rl * 128 + ((sc ^ (rl & 15)) << 3) + off] = (half_t)u;
        }
    // phase 3: stage Dinv block ib (global-side swizzle for 128-wide rows)
    for (int it = 0; it < 8; ++it) {
      int ch = it * 256 + tid;
      int row = ch >> 4, sc = ch & 15;
      const half_t* g = Dinv + (size_t)ib * 16384 + (size_t)row * 128 + ((sc ^ (row & 15)) << 3);
      half_t* l = sD + (size_t)(it * 256 + (tid & 192)) * 8;
      __builtin_amdgcn_global_load_lds(
          (const __attribute__((address_space(1))) uint32_t*)(const void*)g,
          (__attribute__((address_space(3))) uint32_t*)(void*)l, 16, 0, 0);
    }
    __syncthreads();
    // phase 4: WtT-panel = Ut * Dinv^T  (K=128)
    float4v a2[2][4] = {};
#pragma unroll
    for (int kk = 0; kk < 4; ++kk) {
      half8 af[2], bf[4];
#pragma unroll
      for (int i = 0; i < 2; ++i) af[i] = frag128(Us, wr + i * 16 + ln15, kk * 4 + quad);
#pragma unroll
      for (int j = 0; j < 4; ++j) bf[j] = frag128(sD, wc + j * 16 + ln15, kk * 4 + quad);
#pragma unroll
      for (int i = 0; i < 2; ++i)
#pragma unroll
        for (int j = 0; j < 4; ++j)
          a2[i][j] = __builtin_amdgcn_mfma_f32_16x16x32_f16(af[i], bf[j], a2[i][j], 0, 0, 0);
    }
#pragma unroll
    for (int i = 0; i < 2; ++i)
#pragma unroll
      for (int j = 0; j < 4; ++j)
#pragma unroll
        for (int rg = 0; rg < 4; ++rg) {
          int rl = wr + i * 16 + quad * 4 + rg;
          int cl = wc + j * 16 + ln15;
          WtT[(size_t)(m0 + rl) * D_DIM + ib * 128 + cl] = (half_t)a2[i][j][rg];
        }
  }
}

// ---------------------------------------------------------------------------
extern "C" void kernel_launch(void* const* d_in, const int* in_sizes, int n_in,
                              void* d_out, int out_size, void* d_ws, size_t ws_size,
                              hipStream_t stream) {
  (void)in_sizes; (void)n_in; (void)out_size; (void)ws_size;
  const float* X = (const float*)d_in[0];   // (1792, 8192) fp32
  const float* U = (const float*)d_in[1];   // (1792, 1792) fp32
  float* out = (float*)d_out;               // (1792, 8192) fp32

  char* ws = (char*)d_ws;
  half_t* XT   = (half_t*)(ws);                    // 29,360,128 B
  half_t* Vh   = (half_t*)(ws + 29360128);         //  6,422,528 B
  half_t* VhT  = (half_t*)(ws + 35782656);         //  6,422,528 B
  half_t* T16  = (half_t*)(ws + 42205184);         //  6,422,528 B
  half_t* WtT  = (half_t*)(ws + 48627712);         //  6,422,528 B
  half_t* Dinv = (half_t*)(ws + 55050240);         //    458,752 B
  half_t* Pf   = (half_t*)(ws + 55508992);         //  6,422,528 B  (total ~62 MB)

  normalize_rows<<<dim3(D_DIM), dim3(256), 0, stream>>>(U, Vh);
  transpose_x<<<dim3(D_DIM / 64, B_DIM / 64), dim3(256), 0, stream>>>(X, XT);
  // T16 = 2*strict_tril(Vn Vn^T) directly (gram fused with build_T16; fp32 G gone)
  gemm_nt<0><<<dim3(14, 14), dim3(256), 0, stream>>>(Vh, Vh, nullptr, T16,
                                                     D_DIM, D_DIM, D_DIM, D_DIM);
  transpose_h<<<dim3(28, 28), dim3(256), 0, stream>>>(Vh, VhT);
  diag_inv<<<dim3(448), dim3(256), 0, stream>>>(T16, Dinv);
  // one-launch blocked forward substitution: WtT = (T^{-1} 2Vn)^T
  fused_solve<<<dim3(28), dim3(256), 0, stream>>>(T16, Vh, Dinv, WtT);
  // Pf = I - Wt^T Vn :  Pf[m][n] = delta(m,n) - sum_k WtT[m][k]*VhT[n][k]
  gemm_nt<1><<<dim3(14, 14), dim3(256), 0, stream>>>(WtT, VhT, nullptr, Pf,
                                                     D_DIM, D_DIM, D_DIM, D_DIM);
  // out = Pf X :  out[i][j] = sum_k Pf[i][k]*XT[j][k]
  gemm_nt<2><<<dim3(64, 14), dim3(256), 0, stream>>>(Pf, XT, out, nullptr,
                                                     D_DIM, D_DIM, D_DIM, B_DIM);
}